// Round 2
// baseline (260.473 us; speedup 1.0000x reference)
//
#include <hip/hip_runtime.h>
#include <hip/hip_bf16.h>
#include <math.h>

// Problem constants (fixed by setup_inputs): B=2, Cin=Cout=64, H=W=128
#define HWSZ 16384   // H*W
#define NPIX 32768   // B*H*W

// ---------------- Kernel 1: pooled mean over H,W per (b,c) ----------------
__global__ __launch_bounds__(256) void k_pool(const float* __restrict__ inp,
                                              float* __restrict__ pooled) {
    int bc = blockIdx.x;                       // 0..127 = b*64+c
    const float4* p = (const float4*)(inp + (size_t)bc * HWSZ);
    float s = 0.f;
    for (int i = threadIdx.x; i < HWSZ / 4; i += 256) {
        float4 v = p[i];
        s += v.x + v.y + v.z + v.w;
    }
#pragma unroll
    for (int off = 32; off; off >>= 1) s += __shfl_down(s, off, 64);
    __shared__ float ls[4];
    if ((threadIdx.x & 63) == 0) ls[threadIdx.x >> 6] = s;
    __syncthreads();
    if (threadIdx.x == 0)
        pooled[bc] = (ls[0] + ls[1] + ls[2] + ls[3]) * (1.0f / 16384.0f);
}

// ---------------- Kernel 2: r = sigmoid(sum_b pooled @ fc_w^T + fc_b) -> alpha[8]
__global__ void k_r(const float* __restrict__ pooled,
                    const float* __restrict__ fc_w,
                    const float* __restrict__ fc_b,
                    float* __restrict__ alpha) {
    int c = threadIdx.x;                      // 64 threads = 1 wave
    float s = pooled[c] + pooled[64 + c];     // sum over batch of means
#pragma unroll
    for (int j = 0; j < 4; j++) {
        float v = s * fc_w[j * 64 + c];
#pragma unroll
        for (int off = 32; off; off >>= 1) v += __shfl_down(v, off, 64);
        if (c == 0) {
            float z = v + fc_b[j];
            float r = 1.0f / (1.0f + expf(-z));
            alpha[2 * j]     = r;     // q even: alpha = r_j
            alpha[2 * j + 1] = 1.0f;  // q odd:  alpha = 1
        }
    }
}

// ---------------- Kernel 3: transpose weight [o][k] -> [k][o] (k = c*9+j) ----
__global__ __launch_bounds__(256) void k_wt(const float* __restrict__ w,
                                            float* __restrict__ wT) {
    int i = blockIdx.x * 256 + threadIdx.x;   // 36864 = 576*64
    if (i < 36864) {
        int o = i & 63;
        int k = i >> 6;
        wT[i] = w[o * 576 + k];
    }
}

// ---------------- Kernel 4: deform-sample + circle8 blend -> E[c*9+j][pixel] (bf16)
// grid 2048: blockIdx & 511 = pixel tile (64 px); blockIdx >> 9 picks 16 of 64
// channels; each wave (cg) handles 4 channels -> 8192 waves for latency hiding.
__global__ __launch_bounds__(256) void k_sample(const float* __restrict__ inp,
                                                const float* __restrict__ off,
                                                const float* __restrict__ msk,
                                                const float* __restrict__ w8,
                                                const float* __restrict__ alpha,
                                                __hip_bfloat16* __restrict__ E) {
    const int tid   = threadIdx.x;
    const int pl    = tid & 63;      // pixel lane
    const int cg    = tid >> 6;      // wave in block 0..3
    const int tile  = blockIdx.x & 511;
    const int cbase = (blockIdx.x >> 9) * 16 + cg * 4;   // 4 channels per wave
    const int p   = tile * 64 + pl;            // global pixel 0..32767
    const int b   = p >> 14;
    const int hw  = p & (HWSZ - 1);
    const int h   = hw >> 7;
    const int w   = hw & 127;
    const int sp  = h * 128 + w;

    // ---- per-pixel tap setup: weights + base offset + packed (dx,dy) delta ----
    float W00[9], W01[9], W10[9], W11[9];
    int   O00[9], DPK[9];
    const float* offb = off + (size_t)b * 18 * HWSZ + sp;
    const float* mb   = msk + (size_t)b * 9 * HWSZ + sp;
#pragma unroll
    for (int k = 0; k < 9; k++) {
        float oy = offb[(2 * k) * HWSZ];
        float ox = offb[(2 * k + 1) * HWSZ];
        float m  = mb[k * HWSZ];
        float py = (float)(h + k / 3 - 1) + oy;
        float px = (float)(w + k % 3 - 1) + ox;
        float fy = floorf(py), fx = floorf(px);
        float ly = py - fy, lx = px - fx;
        int iy0 = (int)fy, ix0 = (int)fx;
        int iy1 = iy0 + 1, ix1 = ix0 + 1;
        bool vy0 = ((unsigned)iy0 < 128u), vy1 = ((unsigned)iy1 < 128u);
        bool vx0 = ((unsigned)ix0 < 128u), vx1 = ((unsigned)ix1 < 128u);
        float hy = 1.0f - ly, hx = 1.0f - lx;
        W00[k] = (vy0 && vx0) ? hy * hx * m : 0.0f;
        W01[k] = (vy0 && vx1) ? hy * lx * m : 0.0f;
        W10[k] = (vy1 && vx0) ? ly * hx * m : 0.0f;
        W11[k] = (vy1 && vx1) ? ly * lx * m : 0.0f;
        int cy0 = min(max(iy0, 0), 127), cy1 = min(max(iy1, 0), 127);
        int cx0 = min(max(ix0, 0), 127), cx1 = min(max(ix1, 0), 127);
        O00[k] = cy0 * 128 + cx0;
        DPK[k] = (cx1 - cx0) | (((cy1 - cy0) << 7) << 16);  // dx | (dy*128)<<16
    }

    // per-pixel blend coefficients
    float u[8], vv[4];
    const float* w8b = w8 + (size_t)b * 8 * HWSZ + sp;
#pragma unroll
    for (int q = 0; q < 8; q++) {
        float x = w8b[q * HWSZ];
        float a = alpha[q];
        u[q] = x * a;
        if ((q & 1) == 0) vv[q >> 1] = x * (1.0f - a);
    }

    // Pinv_q = P_{(8-q)%8}
    constexpr int PINV[8][9] = {
        {0,1,2,3,4,5,6,7,8},
        {1,2,5,0,4,8,3,6,7},
        {2,5,8,1,4,7,0,3,6},
        {5,8,7,2,4,6,1,0,3},
        {8,7,6,5,4,3,2,1,0},
        {7,6,3,8,4,0,5,2,1},
        {6,3,0,7,4,1,8,5,2},
        {3,0,1,6,4,2,7,8,5}};
    const float SA = 0.5f;          // S^2
    const float SB = 0.20710678f;   // S*(1-S)
    const float SC = 0.08578644f;   // (1-S)^2

    const float* ipb = inp + (size_t)(b * 64 + cbase) * HWSZ;
    for (int cc = 0; cc < 4; cc++) {
        const float* ip = ipb + (size_t)cc * HWSZ;
        float sam[9];
#pragma unroll
        for (int k = 0; k < 9; k++) {
            int i00 = O00[k];
            int dx  = DPK[k] & 0xffff;
            int dy  = DPK[k] >> 16;
            sam[k] = W00[k] * ip[i00]      + W01[k] * ip[i00 + dx] +
                     W10[k] * ip[i00 + dy] + W11[k] * ip[i00 + dx + dy];
        }
        float A[9], Bv[9];
#pragma unroll
        for (int t = 0; t < 9; t++) {
            float a = 0.f, bb = 0.f;
#pragma unroll
            for (int q = 0; q < 8; q++) a += u[q] * sam[PINV[q][t]];
#pragma unroll
            for (int i = 0; i < 4; i++) bb += vv[i] * sam[PINV[2 * i][t]];
            A[t] = a; Bv[t] = bb;
        }
        float Ev[9];
        Ev[0] = SA * A[0] + Bv[0];
        Ev[1] = A[1] + SB * (A[0] + A[2]) + Bv[1];
        Ev[2] = SA * A[2] + Bv[2];
        Ev[3] = A[3] + SB * (A[0] + A[6]) + Bv[3];
        Ev[4] = A[4] + SC * (A[0] + A[2] + A[6] + A[8]) + Bv[4];
        Ev[5] = A[5] + SB * (A[2] + A[8]) + Bv[5];
        Ev[6] = SA * A[6] + Bv[6];
        Ev[7] = A[7] + SB * (A[6] + A[8]) + Bv[7];
        Ev[8] = SA * A[8] + Bv[8];
        int c = cbase + cc;
#pragma unroll
        for (int j = 0; j < 9; j++)
            E[(size_t)(c * 9 + j) * NPIX + p] = __float2bfloat16(Ev[j]);
    }
}

// ---------------- Kernel 5: out = E^T @ wT  (+ per-pixel blended bias) -------
// Wave = 64 lanes = 64 outputs; each wave owns 16 pixels. Weights stream as
// coalesced vector loads; E pixels come in via wave-uniform s_load_dwordx4.
// Output transposed through LDS so stores stay coalesced.
__global__ __launch_bounds__(256) void k_gemm(const __hip_bfloat16* __restrict__ E,
                                              const float* __restrict__ wT,
                                              const float* __restrict__ w8,
                                              const float* __restrict__ bias,
                                              float* __restrict__ out) {
    __shared__ float ls[64 * 65];
    const int tid   = threadIdx.x;
    const int lane  = tid & 63;                 // output index o
    const int wv    = tid >> 6;                 // wave -> 16-pixel chunk
    const int ptile = blockIdx.x * 64;
    const int p0    = __builtin_amdgcn_readfirstlane(ptile + wv * 16);

    float acc[16];
#pragma unroll
    for (int i = 0; i < 16; i++) acc[i] = 0.f;

    // E viewed as uint4 rows of 8 bf16; p0 is a multiple of 16 -> 32B aligned
    const uint4* Eq = (const uint4*)(E + (size_t)p0);
    const float* wp = wT + lane;

#pragma unroll 2
    for (int k = 0; k < 576; k++) {
        float wk = wp[k * 64];                      // coalesced 256B/wave
        uint4 ea = Eq[(size_t)k * (NPIX / 8)];      // px 0..7  (s_load)
        uint4 eb = Eq[(size_t)k * (NPIX / 8) + 1];  // px 8..15 (s_load)
        const unsigned dw[8] = {ea.x, ea.y, ea.z, ea.w, eb.x, eb.y, eb.z, eb.w};
#pragma unroll
        for (int j = 0; j < 8; j++) {
            float elo = __uint_as_float(dw[j] << 16);
            float ehi = __uint_as_float(dw[j] & 0xffff0000u);
            acc[2 * j]     += wk * elo;
            acc[2 * j + 1] += wk * ehi;
        }
    }

    // transpose through LDS: ls[o][px], stride 65 -> conflict-free
#pragma unroll
    for (int i = 0; i < 16; i++) ls[lane * 65 + wv * 16 + i] = acc[i];
    __syncthreads();

    const int pl = tid & 63;
    const int og = tid >> 6;
    const int p  = ptile + pl;
    const int b  = p >> 14;
    const int sp = p & (HWSZ - 1);
    const float* w8b = w8 + (size_t)b * 8 * HWSZ + sp;
    float w8v[8];
#pragma unroll
    for (int q = 0; q < 8; q++) w8v[q] = w8b[q * HWSZ];

#pragma unroll
    for (int i = 0; i < 16; i++) {
        int o = og * 16 + i;
        float bv = 0.f;
#pragma unroll
        for (int q = 0; q < 8; q++) bv += w8v[q] * bias[q * 64 + o];
        out[(size_t)(b * 64 + o) * HWSZ + sp] = ls[o * 65 + pl] + bv;
    }
}

// ---------------- Launch ----------------
extern "C" void kernel_launch(void* const* d_in, const int* in_sizes, int n_in,
                              void* d_out, int out_size, void* d_ws, size_t ws_size,
                              hipStream_t stream) {
    const float* input  = (const float*)d_in[0];
    const float* offset = (const float*)d_in[1];
    const float* mask   = (const float*)d_in[2];
    const float* w_c8   = (const float*)d_in[3];
    const float* weight = (const float*)d_in[4];
    const float* bias   = (const float*)d_in[5];
    const float* fc_w   = (const float*)d_in[6];
    const float* fc_b   = (const float*)d_in[7];
    float* out = (float*)d_out;

    float* wsf    = (float*)d_ws;
    float* wT     = wsf;              // 36864 floats
    float* pooled = wsf + 36864;      // 128 floats
    float* alpha  = wsf + 36992;      // 8 floats
    __hip_bfloat16* E = (__hip_bfloat16*)(wsf + 37120);  // 576*32768 bf16 = 36 MiB

    k_pool<<<dim3(128), dim3(256), 0, stream>>>(input, pooled);
    k_r<<<dim3(1), dim3(64), 0, stream>>>(pooled, fc_w, fc_b, alpha);
    k_wt<<<dim3(144), dim3(256), 0, stream>>>(weight, wT);
    k_sample<<<dim3(2048), dim3(256), 0, stream>>>(input, offset, mask, w_c8, alpha, E);
    k_gemm<<<dim3(512), dim3(256), 0, stream>>>(E, wT, w_c8, bias, out);
}

// Round 3
// 187.615 us; speedup vs baseline: 1.3883x; 1.3883x over previous
//
#include <hip/hip_runtime.h>
#include <hip/hip_bf16.h>
#include <math.h>

// Problem constants (fixed by setup_inputs): B=2, Cin=Cout=64, H=W=128
#define HWSZ 16384   // H*W
#define NPIX 32768   // B*H*W

typedef __attribute__((ext_vector_type(8))) short bf16x8;
typedef __attribute__((ext_vector_type(4))) float f32x4;

__device__ __forceinline__ unsigned pk2(float x, float y) {
    __hip_bfloat16 bx = __float2bfloat16(x), by = __float2bfloat16(y);
    unsigned short ux, uy;
    __builtin_memcpy(&ux, &bx, 2);
    __builtin_memcpy(&uy, &by, 2);
    return (unsigned)ux | ((unsigned)uy << 16);
}

// ---------------- k_pool: per-(b,c) mean over H,W ----------------
__global__ __launch_bounds__(256) void k_pool(const float* __restrict__ inp,
                                              float* __restrict__ pooled) {
    int bc = blockIdx.x;
    const float4* p = (const float4*)(inp + (size_t)bc * HWSZ);
    float s = 0.f;
    for (int i = threadIdx.x; i < HWSZ / 4; i += 256) {
        float4 v = p[i];
        s += v.x + v.y + v.z + v.w;
    }
#pragma unroll
    for (int off = 32; off; off >>= 1) s += __shfl_down(s, off, 64);
    __shared__ float ls[4];
    if ((threadIdx.x & 63) == 0) ls[threadIdx.x >> 6] = s;
    __syncthreads();
    if (threadIdx.x == 0)
        pooled[bc] = (ls[0] + ls[1] + ls[2] + ls[3]) * (1.0f / 16384.0f);
}

// ---------------- k_r: alpha[8] from sigmoid(fc) ----------------
__global__ void k_r(const float* __restrict__ pooled,
                    const float* __restrict__ fc_w,
                    const float* __restrict__ fc_b,
                    float* __restrict__ alpha) {
    int c = threadIdx.x;
    float s = pooled[c] + pooled[64 + c];
#pragma unroll
    for (int j = 0; j < 4; j++) {
        float v = s * fc_w[j * 64 + c];
#pragma unroll
        for (int off = 32; off; off >>= 1) v += __shfl_down(v, off, 64);
        if (c == 0) {
            float z = v + fc_b[j];
            float r = 1.0f / (1.0f + expf(-z));
            alpha[2 * j]     = r;
            alpha[2 * j + 1] = 1.0f;
        }
    }
}

// ---------------- k_wt2: weight f32 [o][c][9] -> bf16 W4[o][c*16+j] zero-padded
__global__ __launch_bounds__(256) void k_wt2(const float* __restrict__ w,
                                             __hip_bfloat16* __restrict__ W4) {
    int i = blockIdx.x * 256 + threadIdx.x;   // 65536 = 64*1024
    int o = i >> 10, k = i & 1023, c = k >> 4, j = k & 15;
    float v = (j < 9) ? w[o * 576 + c * 9 + j] : 0.0f;
    W4[i] = __float2bfloat16(v);
}

// ---------------- k_tap: per-pixel bilinear taps + blend coefs -> ws ----------
__global__ __launch_bounds__(256) void k_tap(const float* __restrict__ off,
                                             const float* __restrict__ msk,
                                             const float* __restrict__ w8,
                                             const float* __restrict__ alpha,
                                             float* __restrict__ taps) {
    int p  = blockIdx.x * 256 + threadIdx.x;   // 0..32767
    int b  = p >> 14;
    int hw = p & (HWSZ - 1);
    int h  = hw >> 7, w = hw & 127, sp = hw;
    float* tw  = taps;                          // [36][NPIX]  W00..W11 per tap
    int*   t00 = (int*)(taps + 36 * NPIX);      // [9][NPIX]
    int*   tdp = (int*)(taps + 45 * NPIX);      // [9][NPIX]
    float* tu  = taps + 54 * NPIX;              // [8][NPIX]
    float* tvv = taps + 62 * NPIX;              // [4][NPIX]

    const float* offb = off + (size_t)b * 18 * HWSZ + sp;
    const float* mb   = msk + (size_t)b * 9 * HWSZ + sp;
#pragma unroll
    for (int k = 0; k < 9; k++) {
        float oy = offb[(2 * k) * HWSZ];
        float ox = offb[(2 * k + 1) * HWSZ];
        float m  = mb[k * HWSZ];
        float py = (float)(h + k / 3 - 1) + oy;
        float px = (float)(w + k % 3 - 1) + ox;
        float fy = floorf(py), fx = floorf(px);
        float ly = py - fy, lx = px - fx;
        int iy0 = (int)fy, ix0 = (int)fx;
        int iy1 = iy0 + 1, ix1 = ix0 + 1;
        bool vy0 = ((unsigned)iy0 < 128u), vy1 = ((unsigned)iy1 < 128u);
        bool vx0 = ((unsigned)ix0 < 128u), vx1 = ((unsigned)ix1 < 128u);
        float hy = 1.0f - ly, hx = 1.0f - lx;
        tw[(k * 4 + 0) * NPIX + p] = (vy0 && vx0) ? hy * hx * m : 0.0f;
        tw[(k * 4 + 1) * NPIX + p] = (vy0 && vx1) ? hy * lx * m : 0.0f;
        tw[(k * 4 + 2) * NPIX + p] = (vy1 && vx0) ? ly * hx * m : 0.0f;
        tw[(k * 4 + 3) * NPIX + p] = (vy1 && vx1) ? ly * lx * m : 0.0f;
        int cy0 = min(max(iy0, 0), 127), cy1 = min(max(iy1, 0), 127);
        int cx0 = min(max(ix0, 0), 127), cx1 = min(max(ix1, 0), 127);
        t00[k * NPIX + p] = cy0 * 128 + cx0;
        tdp[k * NPIX + p] = (cx1 - cx0) | (((cy1 - cy0) << 7) << 16);
    }
    const float* w8b = w8 + (size_t)b * 8 * HWSZ + sp;
#pragma unroll
    for (int q = 0; q < 8; q++) {
        float x = w8b[q * HWSZ];
        float a = alpha[q];
        tu[q * NPIX + p] = x * a;
        if ((q & 1) == 0) tvv[(q >> 1) * NPIX + p] = x * (1.0f - a);
    }
}

// ---------------- k_sample2: gather + circle8 blend -> E4[c][p][16] bf16 ------
// grid 2048: (blockIdx & 511) = 64-px tile; (blockIdx >> 9) = channel quarter.
// Each wave: 4 channels x 64 px. Taps are preloaded (coalesced), not recomputed.
__global__ __launch_bounds__(256) void k_sample2(const float* __restrict__ inp,
                                                 const float* __restrict__ taps,
                                                 __hip_bfloat16* __restrict__ E4) {
    const int tid = threadIdx.x;
    const int pl  = tid & 63;
    const int cg  = tid >> 6;
    const int p   = (blockIdx.x & 511) * 64 + pl;
    const int c0  = (blockIdx.x >> 9) * 16 + cg * 4;
    const int b   = p >> 14;

    const float* tw  = taps;
    const int*   t00 = (const int*)(taps + 36 * NPIX);
    const int*   tdp = (const int*)(taps + 45 * NPIX);
    const float* tu  = taps + 54 * NPIX;
    const float* tvv = taps + 62 * NPIX;

    float W00[9], W01[9], W10[9], W11[9];
    int   O00[9], DPK[9];
#pragma unroll
    for (int k = 0; k < 9; k++) {
        W00[k] = tw[(k * 4 + 0) * NPIX + p];
        W01[k] = tw[(k * 4 + 1) * NPIX + p];
        W10[k] = tw[(k * 4 + 2) * NPIX + p];
        W11[k] = tw[(k * 4 + 3) * NPIX + p];
        O00[k] = t00[k * NPIX + p];
        DPK[k] = tdp[k * NPIX + p];
    }
    float u[8], vv[4];
#pragma unroll
    for (int q = 0; q < 8; q++) u[q] = tu[q * NPIX + p];
#pragma unroll
    for (int q = 0; q < 4; q++) vv[q] = tvv[q * NPIX + p];

    constexpr int PINV[8][9] = {
        {0,1,2,3,4,5,6,7,8},
        {1,2,5,0,4,8,3,6,7},
        {2,5,8,1,4,7,0,3,6},
        {5,8,7,2,4,6,1,0,3},
        {8,7,6,5,4,3,2,1,0},
        {7,6,3,8,4,0,5,2,1},
        {6,3,0,7,4,1,8,5,2},
        {3,0,1,6,4,2,7,8,5}};
    const float SA = 0.5f;
    const float SB = 0.20710678f;
    const float SC = 0.08578644f;

    const float* ipb = inp + (size_t)(b * 64 + c0) * HWSZ;
#pragma unroll 1
    for (int cc = 0; cc < 4; cc++) {
        const float* ip = ipb + (size_t)cc * HWSZ;
        float sam[9];
#pragma unroll
        for (int k = 0; k < 9; k++) {
            int i00 = O00[k];
            int dx  = DPK[k] & 0xffff;
            int dy  = DPK[k] >> 16;
            sam[k] = W00[k] * ip[i00]      + W01[k] * ip[i00 + dx] +
                     W10[k] * ip[i00 + dy] + W11[k] * ip[i00 + dx + dy];
        }
        float A[9], Bv[9];
#pragma unroll
        for (int t = 0; t < 9; t++) {
            float a = 0.f, bb = 0.f;
#pragma unroll
            for (int q = 0; q < 8; q++) a += u[q] * sam[PINV[q][t]];
#pragma unroll
            for (int i = 0; i < 4; i++) bb += vv[i] * sam[PINV[2 * i][t]];
            A[t] = a; Bv[t] = bb;
        }
        float Ev[9];
        Ev[0] = SA * A[0] + Bv[0];
        Ev[1] = A[1] + SB * (A[0] + A[2]) + Bv[1];
        Ev[2] = SA * A[2] + Bv[2];
        Ev[3] = A[3] + SB * (A[0] + A[6]) + Bv[3];
        Ev[4] = A[4] + SC * (A[0] + A[2] + A[6] + A[8]) + Bv[4];
        Ev[5] = A[5] + SB * (A[2] + A[8]) + Bv[5];
        Ev[6] = SA * A[6] + Bv[6];
        Ev[7] = A[7] + SB * (A[6] + A[8]) + Bv[7];
        Ev[8] = SA * A[8] + Bv[8];

        // E4 row (c,p): 16 slots; slots 9..15 multiply zero weights (left as-is)
        size_t dw = ((size_t)(c0 + cc) * NPIX + p) * 8;  // dword index
        uint4 lo;
        lo.x = pk2(Ev[0], Ev[1]);
        lo.y = pk2(Ev[2], Ev[3]);
        lo.z = pk2(Ev[4], Ev[5]);
        lo.w = pk2(Ev[6], Ev[7]);
        ((uint4*)E4)[dw >> 2] = lo;                     // 32B-aligned row base
        ((unsigned*)E4)[dw + 4] = pk2(Ev[8], 0.0f);
    }
}

// ---------------- k_gemm2: MFMA bf16, out[o][p] = W4 . E4 + blended bias ------
// Block: 4 waves x (64 o x 16 px) = 64 o x 64 px. K' = 1024 (16-slot padded).
__global__ __launch_bounds__(256) void k_gemm2(const __hip_bfloat16* __restrict__ E4h,
                                               const __hip_bfloat16* __restrict__ W4h,
                                               const float* __restrict__ w8,
                                               const float* __restrict__ bias,
                                               float* __restrict__ out) {
    __shared__ float lbias[512];
    const int tid = threadIdx.x;
    lbias[tid] = bias[tid];
    lbias[tid + 256] = bias[tid + 256];
    __syncthreads();

    const int l    = tid & 63;
    const int wv   = tid >> 6;
    const int pl   = l & 15;
    const int quad = l >> 4;
    const int p0   = blockIdx.x * 64 + wv * 16;

    const bf16x8* Ep = (const bf16x8*)E4h;
    const bf16x8* Wp = (const bf16x8*)W4h;

    f32x4 acc[4];
#pragma unroll
    for (int i = 0; i < 4; i++) acc[i] = (f32x4){0.f, 0.f, 0.f, 0.f};

    // B-frag: E4[(2s + quad/2)*NPIX + p][ (quad&1)*8 + j ]  (k = quad*8+j)
    size_t bidx = ((size_t)(quad >> 1) * NPIX + p0 + pl) * 2 + (quad & 1);
    // A-frag tile ot: W4[(ot*16+pl)*1024 + s*32 + quad*8]
    size_t aidx = (size_t)pl * 128 + quad;

    for (int s = 0; s < 32; s++) {
        bf16x8 bf = Ep[bidx];
        bidx += 131072;                        // +2 channels = 2*NPIX*2 bf16x8
        bf16x8 a0 = Wp[aidx];
        bf16x8 a1 = Wp[aidx + 2048];
        bf16x8 a2 = Wp[aidx + 4096];
        bf16x8 a3 = Wp[aidx + 6144];
        aidx += 4;
        acc[0] = __builtin_amdgcn_mfma_f32_16x16x32_bf16(a0, bf, acc[0], 0, 0, 0);
        acc[1] = __builtin_amdgcn_mfma_f32_16x16x32_bf16(a1, bf, acc[1], 0, 0, 0);
        acc[2] = __builtin_amdgcn_mfma_f32_16x16x32_bf16(a2, bf, acc[2], 0, 0, 0);
        acc[3] = __builtin_amdgcn_mfma_f32_16x16x32_bf16(a3, bf, acc[3], 0, 0, 0);
    }

    // Epilogue: D element (o = ot*16 + quad*4 + r, px = p0 + pl)
    const int p  = p0 + pl;
    const int b  = p >> 14;
    const int sp = p & (HWSZ - 1);
    float w8v[8];
#pragma unroll
    for (int q = 0; q < 8; q++) w8v[q] = w8[(size_t)b * 8 * HWSZ + q * HWSZ + sp];

#pragma unroll
    for (int ot = 0; ot < 4; ot++) {
#pragma unroll
        for (int r = 0; r < 4; r++) {
            int o = ot * 16 + quad * 4 + r;
            float bv = 0.f;
#pragma unroll
            for (int q = 0; q < 8; q++) bv += w8v[q] * lbias[q * 64 + o];
            out[(size_t)(b * 64 + o) * HWSZ + sp] = acc[ot][r] + bv;
        }
    }
}

// ======================= Fallback path (R1 pipeline, ws < 76 MB) =============
__global__ __launch_bounds__(256) void k_wtF(const float* __restrict__ w,
                                             float* __restrict__ wT) {
    int i = blockIdx.x * 256 + threadIdx.x;
    if (i < 36864) {
        int o = i & 63;
        int k = i >> 6;
        wT[i] = w[o * 576 + k];
    }
}

__global__ __launch_bounds__(256) void k_sampleF(const float* __restrict__ inp,
                                                 const float* __restrict__ off,
                                                 const float* __restrict__ msk,
                                                 const float* __restrict__ w8,
                                                 const float* __restrict__ alpha,
                                                 __hip_bfloat16* __restrict__ E) {
    const int tid = threadIdx.x;
    const int pl  = tid & 63;
    const int cg  = tid >> 6;
    const int p   = blockIdx.x * 64 + pl;
    const int b   = p >> 14;
    const int hw  = p & (HWSZ - 1);
    const int h   = hw >> 7;
    const int w   = hw & 127;
    const int sp  = h * 128 + w;

    float W00[9], W01[9], W10[9], W11[9];
    int   O00[9], O01[9], O10[9], O11[9];
    const float* offb = off + (size_t)b * 18 * HWSZ + sp;
    const float* mb   = msk + (size_t)b * 9 * HWSZ + sp;
#pragma unroll
    for (int k = 0; k < 9; k++) {
        float oy = offb[(2 * k) * HWSZ];
        float ox = offb[(2 * k + 1) * HWSZ];
        float m  = mb[k * HWSZ];
        float py = (float)(h + k / 3 - 1) + oy;
        float px = (float)(w + k % 3 - 1) + ox;
        float fy = floorf(py), fx = floorf(px);
        float ly = py - fy, lx = px - fx;
        int iy0 = (int)fy, ix0 = (int)fx;
        int iy1 = iy0 + 1, ix1 = ix0 + 1;
        bool vy0 = ((unsigned)iy0 < 128u), vy1 = ((unsigned)iy1 < 128u);
        bool vx0 = ((unsigned)ix0 < 128u), vx1 = ((unsigned)ix1 < 128u);
        float hy = 1.0f - ly, hx = 1.0f - lx;
        W00[k] = (vy0 && vx0) ? hy * hx * m : 0.0f;
        W01[k] = (vy0 && vx1) ? hy * lx * m : 0.0f;
        W10[k] = (vy1 && vx0) ? ly * hx * m : 0.0f;
        W11[k] = (vy1 && vx1) ? ly * lx * m : 0.0f;
        int cy0 = min(max(iy0, 0), 127), cy1 = min(max(iy1, 0), 127);
        int cx0 = min(max(ix0, 0), 127), cx1 = min(max(ix1, 0), 127);
        O00[k] = cy0 * 128 + cx0;  O01[k] = cy0 * 128 + cx1;
        O10[k] = cy1 * 128 + cx0;  O11[k] = cy1 * 128 + cx1;
    }
    float u[8], vv[4];
    const float* w8b = w8 + (size_t)b * 8 * HWSZ + sp;
#pragma unroll
    for (int q = 0; q < 8; q++) {
        float x = w8b[q * HWSZ];
        float a = alpha[q];
        u[q] = x * a;
        if ((q & 1) == 0) vv[q >> 1] = x * (1.0f - a);
    }
    constexpr int PINV[8][9] = {
        {0,1,2,3,4,5,6,7,8},
        {1,2,5,0,4,8,3,6,7},
        {2,5,8,1,4,7,0,3,6},
        {5,8,7,2,4,6,1,0,3},
        {8,7,6,5,4,3,2,1,0},
        {7,6,3,8,4,0,5,2,1},
        {6,3,0,7,4,1,8,5,2},
        {3,0,1,6,4,2,7,8,5}};
    const float SA = 0.5f, SB = 0.20710678f, SC = 0.08578644f;
    const float* ipb = inp + (size_t)(b * 64 + cg * 16) * HWSZ;
    for (int cc = 0; cc < 16; cc++) {
        const float* ip = ipb + (size_t)cc * HWSZ;
        float sam[9];
#pragma unroll
        for (int k = 0; k < 9; k++)
            sam[k] = W00[k] * ip[O00[k]] + W01[k] * ip[O01[k]] +
                     W10[k] * ip[O10[k]] + W11[k] * ip[O11[k]];
        float A[9], Bv[9];
#pragma unroll
        for (int t = 0; t < 9; t++) {
            float a = 0.f, bb = 0.f;
#pragma unroll
            for (int q = 0; q < 8; q++) a += u[q] * sam[PINV[q][t]];
#pragma unroll
            for (int i = 0; i < 4; i++) bb += vv[i] * sam[PINV[2 * i][t]];
            A[t] = a; Bv[t] = bb;
        }
        float Ev[9];
        Ev[0] = SA * A[0] + Bv[0];
        Ev[1] = A[1] + SB * (A[0] + A[2]) + Bv[1];
        Ev[2] = SA * A[2] + Bv[2];
        Ev[3] = A[3] + SB * (A[0] + A[6]) + Bv[3];
        Ev[4] = A[4] + SC * (A[0] + A[2] + A[6] + A[8]) + Bv[4];
        Ev[5] = A[5] + SB * (A[2] + A[8]) + Bv[5];
        Ev[6] = SA * A[6] + Bv[6];
        Ev[7] = A[7] + SB * (A[6] + A[8]) + Bv[7];
        Ev[8] = SA * A[8] + Bv[8];
        int c = cg * 16 + cc;
#pragma unroll
        for (int j = 0; j < 9; j++)
            E[(size_t)(c * 9 + j) * NPIX + p] = __float2bfloat16(Ev[j]);
    }
}

__global__ __launch_bounds__(256) void k_gemmF(const __hip_bfloat16* __restrict__ E,
                                               const float* __restrict__ wT,
                                               const float* __restrict__ w8,
                                               const float* __restrict__ bias,
                                               float* __restrict__ out) {
    const int tid = threadIdx.x;
    const int pl  = tid & 63;
    const int og  = tid >> 6;
    const int p   = blockIdx.x * 64 + pl;
    float acc[16];
#pragma unroll
    for (int i = 0; i < 16; i++) acc[i] = 0.f;
#pragma unroll 4
    for (int k = 0; k < 576; k++) {
        float e = __bfloat162float(E[(size_t)k * NPIX + p]);
        const float* wrow = wT + k * 64 + og * 16;
#pragma unroll
        for (int i = 0; i < 16; i++) acc[i] += e * wrow[i];
    }
    const int b  = p >> 14;
    const int sp = p & (HWSZ - 1);
    const float* w8b = w8 + (size_t)b * 8 * HWSZ + sp;
    float w8v[8];
#pragma unroll
    for (int q = 0; q < 8; q++) w8v[q] = w8b[q * HWSZ];
#pragma unroll
    for (int i = 0; i < 16; i++) {
        int o = og * 16 + i;
        float bv = 0.f;
#pragma unroll
        for (int q = 0; q < 8; q++) bv += w8v[q] * bias[q * 64 + o];
        out[(size_t)(b * 64 + o) * HWSZ + sp] = acc[i] + bv;
    }
}

// ---------------- Launch ----------------
extern "C" void kernel_launch(void* const* d_in, const int* in_sizes, int n_in,
                              void* d_out, int out_size, void* d_ws, size_t ws_size,
                              hipStream_t stream) {
    const float* input  = (const float*)d_in[0];
    const float* offset = (const float*)d_in[1];
    const float* mask   = (const float*)d_in[2];
    const float* w_c8   = (const float*)d_in[3];
    const float* weight = (const float*)d_in[4];
    const float* bias   = (const float*)d_in[5];
    const float* fc_w   = (const float*)d_in[6];
    const float* fc_b   = (const float*)d_in[7];
    float* out = (float*)d_out;
    float* wsf = (float*)d_ws;

    if (ws_size >= 75891712ULL) {
        // ws layout (float units):
        //   W4 bf16 [64][1024]      @ 0        (32768 f)
        //   pooled  [128]           @ 32768
        //   alpha   [8]             @ 32896
        //   taps    [66][NPIX]      @ 33024    (2162688 f)
        //   E4 bf16 [64][NPIX][16]  @ 2195712  (16777216 f = 64 MiB)
        __hip_bfloat16* W4 = (__hip_bfloat16*)wsf;
        float* pooled = wsf + 32768;
        float* alpha  = wsf + 32896;
        float* taps   = wsf + 33024;
        __hip_bfloat16* E4 = (__hip_bfloat16*)(wsf + 2195712);

        k_pool<<<dim3(128), dim3(256), 0, stream>>>(input, pooled);
        k_r<<<dim3(1), dim3(64), 0, stream>>>(pooled, fc_w, fc_b, alpha);
        k_wt2<<<dim3(256), dim3(256), 0, stream>>>(weight, W4);
        k_tap<<<dim3(128), dim3(256), 0, stream>>>(offset, mask, w_c8, alpha, taps);
        k_sample2<<<dim3(2048), dim3(256), 0, stream>>>(input, taps, E4);
        k_gemm2<<<dim3(512), dim3(256), 0, stream>>>(E4, W4, w_c8, bias, out);
    } else {
        // R1 fallback: wT @0 (36864), pooled @36864, alpha @36992, E @37120
        float* wT     = wsf;
        float* pooled = wsf + 36864;
        float* alpha  = wsf + 36992;
        __hip_bfloat16* E = (__hip_bfloat16*)(wsf + 37120);
        k_pool<<<dim3(128), dim3(256), 0, stream>>>(input, pooled);
        k_r<<<dim3(1), dim3(64), 0, stream>>>(pooled, fc_w, fc_b, alpha);
        k_wtF<<<dim3(144), dim3(256), 0, stream>>>(weight, wT);
        k_sampleF<<<dim3(512), dim3(256), 0, stream>>>(input, offset, mask, w_c8, alpha, E);
        k_gemmF<<<dim3(512), dim3(256), 0, stream>>>(E, wT, w_c8, bias, out);
    }
}

// Round 4
// 143.503 us; speedup vs baseline: 1.8151x; 1.3074x over previous
//
#include <hip/hip_runtime.h>
#include <hip/hip_bf16.h>
#include <math.h>

// Problem constants (fixed by setup_inputs): B=2, Cin=Cout=64, H=W=128
#define HWSZ 16384   // H*W
#define NPIX 32768   // B*H*W
#define ROWB 2064    // LDS row stride bytes: 1024 bf16 + 8 pad; 516 banks = 4 mod 32

typedef __attribute__((ext_vector_type(8))) short bf16x8;
typedef __attribute__((ext_vector_type(4))) float f32x4;

__device__ __forceinline__ unsigned pk2(float x, float y) {
    __hip_bfloat16 bx = __float2bfloat16(x), by = __float2bfloat16(y);
    unsigned short ux, uy;
    __builtin_memcpy(&ux, &bx, 2);
    __builtin_memcpy(&uy, &by, 2);
    return (unsigned)ux | ((unsigned)uy << 16);
}

// ---------------- k_pool: per-(b,c) mean over H,W (1024 thr -> 16 waves) -----
__global__ __launch_bounds__(1024) void k_pool(const float* __restrict__ inp,
                                               float* __restrict__ pooled) {
    int bc = blockIdx.x;
    const float4* p4 = (const float4*)(inp + (size_t)bc * HWSZ);
    float s = 0.f;
    for (int i = threadIdx.x; i < HWSZ / 4; i += 1024) {
        float4 v = p4[i];
        s += v.x + v.y + v.z + v.w;
    }
#pragma unroll
    for (int off = 32; off; off >>= 1) s += __shfl_down(s, off, 64);
    __shared__ float ls[16];
    if ((threadIdx.x & 63) == 0) ls[threadIdx.x >> 6] = s;
    __syncthreads();
    if (threadIdx.x == 0) {
        float t = 0.f;
#pragma unroll
        for (int i = 0; i < 16; i++) t += ls[i];
        pooled[bc] = t * (1.0f / 16384.0f);
    }
}

// ---------------- k_r: alpha[8] from sigmoid(fc) ----------------
__global__ void k_r(const float* __restrict__ pooled,
                    const float* __restrict__ fc_w,
                    const float* __restrict__ fc_b,
                    float* __restrict__ alpha) {
    int c = threadIdx.x;
    float s = pooled[c] + pooled[64 + c];
#pragma unroll
    for (int j = 0; j < 4; j++) {
        float v = s * fc_w[j * 64 + c];
#pragma unroll
        for (int off = 32; off; off >>= 1) v += __shfl_down(v, off, 64);
        if (c == 0) {
            float z = v + fc_b[j];
            float r = 1.0f / (1.0f + expf(-z));
            alpha[2 * j]     = r;
            alpha[2 * j + 1] = 1.0f;
        }
    }
}

// ---------------- k_wfrag: weight -> MFMA A-fragment order, bf16 -------------
// Afrag[((ot*32 + s)*64 + lane)*8 + e]; lane=(quad<<4)|m; A[m][k], k=s*32+quad*8+e
// k -> (c = k>>4, j = k&15), zero for j>=9. 65536 elements.
__global__ __launch_bounds__(256) void k_wfrag(const float* __restrict__ w,
                                               __hip_bfloat16* __restrict__ Afrag) {
    int i = blockIdx.x * 256 + threadIdx.x;   // 0..65535
    int ot = i >> 14, s = (i >> 9) & 31, l = (i >> 3) & 63, e = i & 7;
    int m = l & 15, quad = l >> 4;
    int o = ot * 16 + m;
    int k = s * 32 + quad * 8 + e;
    int c = k >> 4, j = k & 15;
    float v = (j < 9) ? w[o * 576 + c * 9 + j] : 0.0f;
    Afrag[i] = __float2bfloat16(v);
}

// ---------------- k_tap2: per-(k,pixel) bilinear taps + blend coefs ----------
// blocks 0..1151: (k = blk>>7, p-tile); blocks 1152..1279: u/vv arrays.
// IPK pack: pairbase(14b) | dy<<14 | s0<<15 | s1<<16; pair = [v[a], v[a+1]].
__global__ __launch_bounds__(256) void k_tap2(const float* __restrict__ off,
                                              const float* __restrict__ msk,
                                              const float* __restrict__ w8,
                                              const float* __restrict__ alpha,
                                              float* __restrict__ taps) {
    float* tw  = taps;                       // [36][NPIX]
    int*   tip = (int*)(taps + 36 * NPIX);   // [9][NPIX]
    float* tu  = taps + 45 * NPIX;           // [8][NPIX]
    float* tvv = taps + 53 * NPIX;           // [4][NPIX]

    if (blockIdx.x < 1152) {
        int k = blockIdx.x >> 7;                       // 0..8 (uniform)
        int p = ((blockIdx.x & 127) << 8) + threadIdx.x;
        int b = p >> 14, sp = p & (HWSZ - 1);
        int h = sp >> 7, w = sp & 127;
        float oy = off[(size_t)b * 18 * HWSZ + (2 * k) * HWSZ + sp];
        float ox = off[(size_t)b * 18 * HWSZ + (2 * k + 1) * HWSZ + sp];
        float m  = msk[(size_t)b * 9 * HWSZ + k * HWSZ + sp];
        float py = (float)(h + k / 3 - 1) + oy;
        float px = (float)(w + k % 3 - 1) + ox;
        float fy = floorf(py), fx = floorf(px);
        float ly = py - fy, lx = px - fx;
        int iy0 = (int)fy, ix0 = (int)fx;
        int iy1 = iy0 + 1, ix1 = ix0 + 1;
        bool vy0 = ((unsigned)iy0 < 128u), vy1 = ((unsigned)iy1 < 128u);
        bool vx0 = ((unsigned)ix0 < 128u), vx1 = ((unsigned)ix1 < 128u);
        float hy = 1.0f - ly, hx = 1.0f - lx;
        tw[(k * 4 + 0) * NPIX + p] = (vy0 && vx0) ? hy * hx * m : 0.0f;
        tw[(k * 4 + 1) * NPIX + p] = (vy0 && vx1) ? hy * lx * m : 0.0f;
        tw[(k * 4 + 2) * NPIX + p] = (vy1 && vx0) ? ly * hx * m : 0.0f;
        tw[(k * 4 + 3) * NPIX + p] = (vy1 && vx1) ? ly * lx * m : 0.0f;
        int cy0 = min(max(iy0, 0), 127), cy1 = min(max(iy1, 0), 127);
        int cx0 = min(max(ix0, 0), 127), cx1 = min(max(ix1, 0), 127);
        int a  = min(cx0, 126);
        int s0 = cx0 - a, s1 = cx1 - a, dy = cy1 - cy0;
        tip[k * NPIX + p] = (cy0 * 128 + a) | (dy << 14) | (s0 << 15) | (s1 << 16);
    } else {
        int p = ((blockIdx.x - 1152) << 8) + threadIdx.x;
        int b = p >> 14, sp = p & (HWSZ - 1);
        const float* w8b = w8 + (size_t)b * 8 * HWSZ + sp;
#pragma unroll
        for (int q = 0; q < 8; q++) {
            float x = w8b[q * HWSZ];
            float a = alpha[q];
            tu[q * NPIX + p] = x * a;
            if ((q & 1) == 0) tvv[(q >> 1) * NPIX + p] = x * (1.0f - a);
        }
    }
}

// ---------------- k_fused: sample+blend into LDS tile, then MFMA GEMM --------
// Block = 16 px x 64 in-ch x 64 out-ch. Phase 1: thread (pl=tid&15, cq=tid>>4)
// samples 4 channels into E_lds[px][k=c*16+j] (bf16, zero-padded). Phase 2:
// wave wv computes o-tile wv (16 o) x 16 px via 32 MFMA steps.
__global__ __launch_bounds__(256) void k_fused(const float* __restrict__ inp,
                                               const float* __restrict__ taps,
                                               const __hip_bfloat16* __restrict__ Afrag,
                                               const float* __restrict__ w8,
                                               const float* __restrict__ bias,
                                               float* __restrict__ out) {
    __shared__ __attribute__((aligned(16))) char els[16 * ROWB];

    const int tid = threadIdx.x;
    {   // ---------------- phase 1: sample ----------------
        const int pl = tid & 15;
        const int cq = tid >> 4;
        const int p  = blockIdx.x * 16 + pl;
        const int b  = p >> 14;

        const float* tw  = taps;
        const int*   tip = (const int*)(taps + 36 * NPIX);
        const float* tu  = taps + 45 * NPIX;
        const float* tvv = taps + 53 * NPIX;

        float W00[9], W01[9], W10[9], W11[9];
        int   IPK[9];
#pragma unroll
        for (int k = 0; k < 9; k++) {
            W00[k] = tw[(k * 4 + 0) * NPIX + p];
            W01[k] = tw[(k * 4 + 1) * NPIX + p];
            W10[k] = tw[(k * 4 + 2) * NPIX + p];
            W11[k] = tw[(k * 4 + 3) * NPIX + p];
            IPK[k] = tip[k * NPIX + p];
        }
        float u[8], vv[4];
#pragma unroll
        for (int q = 0; q < 8; q++) u[q] = tu[q * NPIX + p];
#pragma unroll
        for (int q = 0; q < 4; q++) vv[q] = tvv[q * NPIX + p];

        constexpr int PINV[8][9] = {
            {0,1,2,3,4,5,6,7,8},
            {1,2,5,0,4,8,3,6,7},
            {2,5,8,1,4,7,0,3,6},
            {5,8,7,2,4,6,1,0,3},
            {8,7,6,5,4,3,2,1,0},
            {7,6,3,8,4,0,5,2,1},
            {6,3,0,7,4,1,8,5,2},
            {3,0,1,6,4,2,7,8,5}};
        const float SA = 0.5f, SB = 0.20710678f, SC = 0.08578644f;

        const float* ipb = inp + (size_t)(b * 64 + cq * 4) * HWSZ;
#pragma unroll 1
        for (int cc = 0; cc < 4; cc++) {
            const float* ip = ipb + (size_t)cc * HWSZ;
            float sam[9];
#pragma unroll
            for (int k = 0; k < 9; k++) {
                int pk   = IPK[k];
                int base = pk & 16383;
                int dy   = (pk >> 14) & 1;
                int s0   = (pk >> 15) & 1;
                int s1   = (pk >> 16) & 1;
                float2 fa, fb;
                __builtin_memcpy(&fa, ip + base, sizeof(float2));
                __builtin_memcpy(&fb, ip + base + (dy << 7), sizeof(float2));
                float v00 = s0 ? fa.y : fa.x;
                float v01 = s1 ? fa.y : fa.x;
                float v10 = s0 ? fb.y : fb.x;
                float v11 = s1 ? fb.y : fb.x;
                sam[k] = W00[k] * v00 + W01[k] * v01 + W10[k] * v10 + W11[k] * v11;
            }
            float A[9], Bv[9];
#pragma unroll
            for (int t = 0; t < 9; t++) {
                float a = 0.f, bb = 0.f;
#pragma unroll
                for (int q = 0; q < 8; q++) a += u[q] * sam[PINV[q][t]];
#pragma unroll
                for (int i = 0; i < 4; i++) bb += vv[i] * sam[PINV[2 * i][t]];
                A[t] = a; Bv[t] = bb;
            }
            float Ev[9];
            Ev[0] = SA * A[0] + Bv[0];
            Ev[1] = A[1] + SB * (A[0] + A[2]) + Bv[1];
            Ev[2] = SA * A[2] + Bv[2];
            Ev[3] = A[3] + SB * (A[0] + A[6]) + Bv[3];
            Ev[4] = A[4] + SC * (A[0] + A[2] + A[6] + A[8]) + Bv[4];
            Ev[5] = A[5] + SB * (A[2] + A[8]) + Bv[5];
            Ev[6] = SA * A[6] + Bv[6];
            Ev[7] = A[7] + SB * (A[6] + A[8]) + Bv[7];
            Ev[8] = SA * A[8] + Bv[8];

            int c = cq * 4 + cc;
            uint4 q0, q1;
            q0.x = pk2(Ev[0], Ev[1]);
            q0.y = pk2(Ev[2], Ev[3]);
            q0.z = pk2(Ev[4], Ev[5]);
            q0.w = pk2(Ev[6], Ev[7]);
            q1.x = pk2(Ev[8], 0.0f);
            q1.y = 0u; q1.z = 0u; q1.w = 0u;
            char* dst = els + pl * ROWB + c * 32;
            *(uint4*)dst = q0;
            *(uint4*)(dst + 16) = q1;
        }
    }
    __syncthreads();

    // ---------------- phase 2: MFMA GEMM ----------------
    const int l    = tid & 63;
    const int wv   = tid >> 6;            // o-tile
    const int pl16 = l & 15;
    const int quad = l >> 4;

    const bf16x8* Ap = (const bf16x8*)Afrag;
    const bf16x8* Bp = (const bf16x8*)(els + pl16 * ROWB + quad * 16);

    f32x4 acc = (f32x4){0.f, 0.f, 0.f, 0.f};
    size_t ai = (size_t)(wv * 32) * 64 + l;
#pragma unroll 4
    for (int s = 0; s < 32; s++) {
        bf16x8 av = Ap[ai + (size_t)s * 64];
        bf16x8 bv = Bp[s * 4];
        acc = __builtin_amdgcn_mfma_f32_16x16x32_bf16(av, bv, acc, 0, 0, 0);
    }

    // epilogue: D row = quad*4 + r (o-offset), col = pl16 (px)
    const int pp  = blockIdx.x * 16 + pl16;
    const int bb  = pp >> 14;
    const int spp = pp & (HWSZ - 1);
    float w8v[8];
#pragma unroll
    for (int q = 0; q < 8; q++) w8v[q] = w8[(size_t)bb * 8 * HWSZ + q * HWSZ + spp];

#pragma unroll
    for (int r = 0; r < 4; r++) {
        int o = wv * 16 + quad * 4 + r;
        float bv = 0.f;
#pragma unroll
        for (int q = 0; q < 8; q++) bv += w8v[q] * bias[q * 64 + o];
        out[(size_t)(bb * 64 + o) * HWSZ + spp] = acc[r] + bv;
    }
}

// ---------------- Launch ----------------
extern "C" void kernel_launch(void* const* d_in, const int* in_sizes, int n_in,
                              void* d_out, int out_size, void* d_ws, size_t ws_size,
                              hipStream_t stream) {
    const float* input  = (const float*)d_in[0];
    const float* offset = (const float*)d_in[1];
    const float* mask   = (const float*)d_in[2];
    const float* w_c8   = (const float*)d_in[3];
    const float* weight = (const float*)d_in[4];
    const float* bias   = (const float*)d_in[5];
    const float* fc_w   = (const float*)d_in[6];
    const float* fc_b   = (const float*)d_in[7];
    float* out = (float*)d_out;
    float* wsf = (float*)d_ws;

    // ws layout (float units):
    //   Afrag bf16 [65536]   @ 0        (32768 f)
    //   pooled [128]         @ 32768
    //   alpha  [8]           @ 32896
    //   taps   [57][NPIX]    @ 33024    (1867776 f)  -> total 7.6 MB
    __hip_bfloat16* Afrag = (__hip_bfloat16*)wsf;
    float* pooled = wsf + 32768;
    float* alpha  = wsf + 32896;
    float* taps   = wsf + 33024;

    k_pool<<<dim3(128), dim3(1024), 0, stream>>>(input, pooled);
    k_r<<<dim3(1), dim3(64), 0, stream>>>(pooled, fc_w, fc_b, alpha);
    k_wfrag<<<dim3(256), dim3(256), 0, stream>>>(weight, Afrag);
    k_tap2<<<dim3(1280), dim3(256), 0, stream>>>(offset, mask, w_c8, alpha, taps);
    k_fused<<<dim3(2048), dim3(256), 0, stream>>>(input, taps, Afrag, w_c8, bias, out);
}